// Round 13
// baseline (135.270 us; speedup 1.0000x reference)
//
#include <hip/hip_runtime.h>
#include <hip/hip_bf16.h>
#include <stdint.h>

typedef __hip_bfloat16 bf16;
typedef __bf16 bf16x8 __attribute__((ext_vector_type(8)));
typedef float f32x4 __attribute__((ext_vector_type(4)));
typedef unsigned short u16x8 __attribute__((ext_vector_type(8)));

#define HID   768
#define SEQL  40
#define TOK   185          // 40 text + 1 cls + 144 patches
#define NP    144
#define PD2   12
#define KDIM  3072
#define IMGSZ 384
#define IMG2  147456       // 384*384

// ws layout: [0, 56623104) pixel bf16 ; [56623104, 61341696) conv_w bf16 ; then int tables
#define WSB_PIX 0
#define WSB_W   56623104
#define WSB_INT 61341696
#define WS_DST 0
#define WS_SRC 9216
#define WS_MV  18432
#define WS_XH  27648
#define WS_XW  27712

#define EMB_ELEMS (64 * TOK * HID)

// fused pre-kernel block ranges
#define NB_PIXC 2048
#define NB_WC   128
#define NB_TEXT (64 * SEQL)
#define BID_WC   NB_PIXC
#define BID_TEXT (NB_PIXC + NB_WC)
#define BID_PREP (BID_TEXT + NB_TEXT)
#define BID_CLS  (BID_PREP + 64)
#define NB_TOTAL (BID_CLS + 64)

#define N8_PIX (28311552 / 8)
#define N8_W   (2359296 / 8)

__device__ __forceinline__ unsigned short f2bu(float x) {   // f32 -> bf16 bits, RNE
    uint32_t u = __float_as_uint(x);
    return (unsigned short)((u + 0x7FFFu + ((u >> 16) & 1u)) >> 16);
}

// ---------------------------------------------------------------- fused pre: casts + text LN + prep + cls/masks
__global__ __launch_bounds__(256) void pre_kernel(
    const float* __restrict__ pixf, unsigned short* __restrict__ pixb,
    const float* __restrict__ Wc, unsigned short* __restrict__ wb,
    const int* __restrict__ ids, const int* __restrict__ tts,
    const float* __restrict__ wemb, const float* __restrict__ ptext,
    const float* __restrict__ ttemb, const float* __restrict__ g,
    const float* __restrict__ be, const float* __restrict__ modal,
    const int* __restrict__ pmask, const float* __restrict__ cls,
    const float* __restrict__ vpos, const int* __restrict__ tti,
    const int* __restrict__ attn, int* __restrict__ ws,
    float* __restrict__ out) {
    int bid = blockIdx.x, tid = threadIdx.x;
    if (bid < NB_PIXC) {
        for (int i = bid * 256 + tid; i < N8_PIX; i += NB_PIXC * 256) {
            f32x4 a = ((const f32x4*)pixf)[2 * i];
            f32x4 b = ((const f32x4*)pixf)[2 * i + 1];
            u16x8 r;
#pragma unroll
            for (int j = 0; j < 4; j++) r[j] = f2bu(a[j]);
#pragma unroll
            for (int j = 0; j < 4; j++) r[4 + j] = f2bu(b[j]);
            ((u16x8*)pixb)[i] = r;
        }
    } else if (bid < BID_TEXT) {
        for (int i = (bid - BID_WC) * 256 + tid; i < N8_W; i += NB_WC * 256) {
            f32x4 a = ((const f32x4*)Wc)[2 * i];
            f32x4 b = ((const f32x4*)Wc)[2 * i + 1];
            u16x8 r;
#pragma unroll
            for (int j = 0; j < 4; j++) r[j] = f2bu(a[j]);
#pragma unroll
            for (int j = 0; j < 4; j++) r[4 + j] = f2bu(b[j]);
            ((u16x8*)wb)[i] = r;
        }
    } else if (bid < BID_PREP) {
        int blk = bid - BID_TEXT;
        int b = blk / SEQL, s = blk % SEQL;
        int id = ids[b * SEQL + s];
        int tt = tts[b * SEQL + s];
        const float* wr = wemb + (size_t)id * HID;
        const float* tr = ttemb + (size_t)tt * HID;
        const float* pr = ptext + s * HID;
        float x[3], s1 = 0.f, s2 = 0.f;
#pragma unroll
        for (int k = 0; k < 3; k++) {
            int n = tid + k * 256;
            float xv = wr[n] + tr[n] + pr[n];
            x[k] = xv; s1 += xv; s2 += xv * xv;
        }
        for (int off = 32; off; off >>= 1) {
            s1 += __shfl_down(s1, off);
            s2 += __shfl_down(s2, off);
        }
        __shared__ float red[8];
        int lane = tid & 63, wid = tid >> 6;
        if (lane == 0) { red[wid] = s1; red[4 + wid] = s2; }
        __syncthreads();
        float ts1 = red[0] + red[1] + red[2] + red[3];
        float ts2 = red[4] + red[5] + red[6] + red[7];
        float mu = ts1 * (1.0f / HID);
        float var = ts2 * (1.0f / HID) - mu * mu;
        float rstd = rsqrtf(var + 1e-12f);
        float* orow = out + ((size_t)(b * TOK + s)) * HID;
#pragma unroll
        for (int k = 0; k < 3; k++) {
            int n = tid + k * 256;
            orow[n] = (x[k] - mu) * rstd * g[n] + be[n] + modal[n];
        }
    } else if (bid < BID_CLS) {
        int b = bid - BID_PREP;
        __shared__ int v[NP];
        if (tid < NP) {
            int i = tid / PD2, j = tid % PD2;
            v[tid] = pmask[(size_t)b * IMG2 + (size_t)(i * 32) * IMGSZ + (j * 32)];
        }
        __syncthreads();
        if (tid == 0) {
            int nv = 0;
            for (int p = 0; p < NP; p++) nv += (v[p] != 0);
            int cv = 0, ci = 0;
            for (int p = 0; p < NP; p++) {
                int d = v[p] ? (cv++) : (nv + ci++);
                ws[WS_DST + b * NP + p] = d;
                ws[WS_SRC + b * NP + d] = p;
                ws[WS_MV + b * NP + p] = v[p];
            }
            int h = 0, w = 0;
            for (int i = 0; i < PD2; i++) h += v[i * PD2];
            for (int j = 0; j < PD2; j++) w += v[j];
            ws[WS_XH + b] = h;
            ws[WS_XW + b] = w;
        }
    } else {
        int b = bid - BID_CLS;
        int tt = *tti;
        const float* modalr = modal + tt * HID;
        float* orow = out + ((size_t)(b * TOK + SEQL)) * HID;
#pragma unroll
        for (int k = 0; k < 3; k++) {
            int n = tid + k * 256;
            orow[n] = cls[n] + vpos[n] + modalr[n];
        }
        __shared__ int v2[NP];
        if (tid < NP) {
            int i = tid / PD2, j = tid % PD2;
            v2[tid] = pmask[(size_t)b * IMG2 + (size_t)(i * 32) * IMGSZ + (j * 32)];
        }
        __syncthreads();
        __shared__ int srcl[NP];
        if (tid == 0) {
            int nv = 0;
            for (int p = 0; p < NP; p++) nv += (v2[p] != 0);
            int cv = 0, ci = 0;
            for (int p = 0; p < NP; p++) {
                int d = v2[p] ? (cv++) : (nv + ci++);
                srcl[d] = p;
            }
        }
        __syncthreads();
        float* om = out + (size_t)EMB_ELEMS + (size_t)b * TOK;
        if (tid < TOK) {
            float mv;
            if (tid < SEQL) mv = (float)attn[b * SEQL + tid];
            else if (tid == SEQL) mv = 1.0f;
            else mv = (float)v2[srcl[tid - (SEQL + 1)]];
            om[tid] = mv;
        }
    }
}

// ---------------------------------------------------------------- conv GEMM
// 128x64 tiles, 64x32 wave tiles, 2-phase dbuf (1 barrier/K-step), 48 KB LDS -> 3 blocks/CU.
__global__ __launch_bounds__(256, 3) void gemm_kernel(
    const bf16* __restrict__ pix, const bf16* __restrict__ W,
    const float* __restrict__ bias, const float* __restrict__ vpos,
    const float* __restrict__ modal, const int* __restrict__ tti,
    const int* __restrict__ ws, float* __restrict__ out) {
    __shared__ unsigned short As[2 * 128 * 64];   // 32 KB
    __shared__ unsigned short Bs[2 * 64 * 64];    // 16 KB

    int bid = blockIdx.x;
    int swz = (bid & 7) * 108 + (bid >> 3);  // 864 = 8*108, bijective XCD swizzle
    int bm = swz / 12, bn = swz - bm * 12;   // n fastest: 12 blocks share an A panel
    int m0 = bm << 7, n0 = bn << 6;

    int tid = threadIdx.x;
    int lane = tid & 63, wid = tid >> 6;
    int wm = wid >> 1, wn = wid & 1;         // 2x2 wave grid, wave tile 64x32

    // staging: thread covers LDS slot (row, kof); source k pre-swizzled (rule 21)
    int kof = (tid & 7) << 3;                // dest k offset within BK=64
    size_t apix[4]; int kofsA[4];
#pragma unroll
    for (int r = 0; r < 4; r++) {
        int row = (tid >> 3) + r * 32;       // 0..127
        kofsA[r] = kof ^ ((row & 7) << 3);
        int gm = m0 + row;
        int b_ = gm / NP; int p_ = gm - b_ * NP;
        int ii = p_ / PD2, jj = p_ - ii * PD2;
        apix[r] = (size_t)(b_ * 3) * IMG2 + (size_t)(ii * 32) * IMGSZ + (jj * 32);
    }
    size_t wbase[2]; int kofsB[2];
#pragma unroll
    for (int r = 0; r < 2; r++) {
        int row = (tid >> 3) + r * 32;       // 0..63
        kofsB[r] = kof ^ ((row & 7) << 3);
        wbase[r] = (size_t)(n0 + row) * KDIM + kofsB[r];
    }

    f32x4 acc[4][2];
#pragma unroll
    for (int a = 0; a < 4; a++)
#pragma unroll
        for (int c = 0; c < 2; c++) acc[a][c] = (f32x4){0.f, 0.f, 0.f, 0.f};

#define STAGE(BUF, KT)                                                              \
    {                                                                               \
        _Pragma("unroll")                                                           \
        for (int r = 0; r < 4; r++) {                                               \
            int k = (KT) + kofsA[r];                                                \
            int ci = k >> 10; int rem = k & 1023;                                   \
            size_t cioff = (size_t)ci * IMG2 + (size_t)(rem >> 5) * IMGSZ + (rem & 31); \
            const bf16* ga = pix + apix[r] + cioff;                                 \
            unsigned short* la = As + (BUF) * 8192 + r * 2048 + wid * 512;          \
            __builtin_amdgcn_global_load_lds(                                       \
                (const __attribute__((address_space(1))) unsigned int*)ga,          \
                (__attribute__((address_space(3))) unsigned int*)la, 16, 0, 0);     \
        }                                                                           \
        _Pragma("unroll")                                                           \
        for (int r = 0; r < 2; r++) {                                               \
            const bf16* gb = W + wbase[r] + (KT);                                   \
            unsigned short* lb = Bs + (BUF) * 4096 + r * 2048 + wid * 512;          \
            __builtin_amdgcn_global_load_lds(                                       \
                (const __attribute__((address_space(1))) unsigned int*)gb,          \
                (__attribute__((address_space(3))) unsigned int*)lb, 16, 0, 0);     \
        }                                                                           \
    }

#define COMPUTE(BUF)                                                                \
    {                                                                               \
        _Pragma("unroll")                                                           \
        for (int ks = 0; ks < 2; ks++) {                                            \
            int kb = (ks << 5) + ((lane >> 4) << 3);                                \
            bf16x8 af[4], bfr[2];                                                   \
            _Pragma("unroll")                                                       \
            for (int mi = 0; mi < 4; mi++) {                                        \
                int row = (wm << 6) + (mi << 4) + (lane & 15);                      \
                af[mi] = *(const bf16x8*)&As[(BUF) * 8192 + row * 64 + (kb ^ ((row & 7) << 3))]; \
            }                                                                       \
            _Pragma("unroll")                                                       \
            for (int nj = 0; nj < 2; nj++) {                                        \
                int row = (wn << 5) + (nj << 4) + (lane & 15);                      \
                bfr[nj] = *(const bf16x8*)&Bs[(BUF) * 4096 + row * 64 + (kb ^ ((row & 7) << 3))]; \
            }                                                                       \
            __builtin_amdgcn_s_setprio(1);                                          \
            _Pragma("unroll")                                                       \
            for (int mi = 0; mi < 4; mi++)                                          \
                _Pragma("unroll")                                                   \
                for (int nj = 0; nj < 2; nj++)                                      \
                    acc[mi][nj] = __builtin_amdgcn_mfma_f32_16x16x32_bf16(          \
                        af[mi], bfr[nj], acc[mi][nj], 0, 0, 0);                     \
            __builtin_amdgcn_s_setprio(0);                                          \
        }                                                                           \
    }

    STAGE(0, 0);
    for (int kt = 0; kt < KDIM; kt += 64) {
        int buf = (kt >> 6) & 1;
        __syncthreads();                     // drains stage -> buf ready
        if (kt + 64 < KDIM) STAGE(buf ^ 1, kt + 64);   // issue next tile early
        COMPUTE(buf);
    }
#undef STAGE
#undef COMPUTE

    // -------- epilogue: +bias +bilinear pos +modality, scatter to token rows (f32 out)
    int tt = *tti;
    const float* modalr = modal + tt * HID;
    int r16 = lane >> 4, c16 = lane & 15;
#pragma unroll
    for (int mi = 0; mi < 4; mi++) {
#pragma unroll
        for (int reg = 0; reg < 4; reg++) {
            int gm = m0 + (wm << 6) + (mi << 4) + (r16 << 2) + reg;
            int b_ = gm / NP; int p_ = gm - b_ * NP;
            int ii = p_ / PD2, jj = p_ - ii * PD2;
            int h = ws[WS_XH + b_], w = ws[WS_XW + b_];
            float hf = (float)((h - 1) > 1 ? (h - 1) : 1);
            float wf = (float)((w - 1) > 1 ? (w - 1) : 1);
            float ry = (float)(ii * (PD2 - 1)) / hf;
            float rx = (float)(jj * (PD2 - 1)) / wf;
            int y0 = (int)floorf(ry); y0 = y0 < 0 ? 0 : (y0 > PD2 - 1 ? PD2 - 1 : y0);
            int x0 = (int)floorf(rx); x0 = x0 < 0 ? 0 : (x0 > PD2 - 1 ? PD2 - 1 : x0);
            int y1 = y0 + 1 > PD2 - 1 ? PD2 - 1 : y0 + 1;
            int x1 = x0 + 1 > PD2 - 1 ? PD2 - 1 : x0 + 1;
            float wy = ry - (float)y0, wx = rx - (float)x0;
            float vs = ((ii < h) && (jj < w)) ? 1.0f : 0.0f;
            float w00 = (1.f - wy) * (1.f - wx) * vs, w01 = (1.f - wy) * wx * vs;
            float w10 = wy * (1.f - wx) * vs, w11 = wy * wx * vs;
            const float* p00 = vpos + (size_t)(1 + y0 * PD2 + x0) * HID;
            const float* p01 = vpos + (size_t)(1 + y0 * PD2 + x1) * HID;
            const float* p10 = vpos + (size_t)(1 + y1 * PD2 + x0) * HID;
            const float* p11 = vpos + (size_t)(1 + y1 * PD2 + x1) * HID;
            int drow = ws[WS_DST + b_ * NP + p_];
            float* orow = out + ((size_t)(b_ * TOK + SEQL + 1 + drow)) * HID;
#pragma unroll
            for (int nj = 0; nj < 2; nj++) {
                int n = n0 + (wn << 5) + (nj << 4) + c16;
                float pos = w00 * p00[n] + w01 * p01[n] + w10 * p10[n] + w11 * p11[n];
                orow[n] = acc[mi][nj][reg] + bias[n] + pos + modalr[n];
            }
        }
    }
}

// ---------------------------------------------------------------- launch
extern "C" void kernel_launch(void* const* d_in, const int* in_sizes, int n_in,
                              void* d_out, int out_size, void* d_ws, size_t ws_size,
                              hipStream_t stream) {
    const int* ids = (const int*)d_in[0];
    const int* attn = (const int*)d_in[1];
    const int* tts = (const int*)d_in[2];
    const float* pix = (const float*)d_in[3];
    const int* pmask = (const int*)d_in[4];
    const float* wemb = (const float*)d_in[5];
    const float* ptext = (const float*)d_in[6];
    const float* ttemb = (const float*)d_in[7];
    const float* g = (const float*)d_in[8];
    const float* be = (const float*)d_in[9];
    const float* cls = (const float*)d_in[10];
    const float* Wc = (const float*)d_in[11];
    const float* bias = (const float*)d_in[12];
    const float* vpos = (const float*)d_in[13];
    const float* modal = (const float*)d_in[14];
    const int* tti = (const int*)d_in[15];
    float* out = (float*)d_out;

    unsigned short* pixb = (unsigned short*)((char*)d_ws + WSB_PIX);
    unsigned short* wb = (unsigned short*)((char*)d_ws + WSB_W);
    int* wsi = (int*)((char*)d_ws + WSB_INT);

    pre_kernel<<<NB_TOTAL, 256, 0, stream>>>(pix, pixb, Wc, wb, ids, tts, wemb, ptext,
                                             ttemb, g, be, modal, pmask, cls, vpos, tti,
                                             attn, wsi, out);
    gemm_kernel<<<864, 256, 0, stream>>>((const bf16*)pixb, (const bf16*)wb,
                                         bias, vpos, modal, tti, wsi, out);
}

// Round 14
// 104.683 us; speedup vs baseline: 1.2922x; 1.2922x over previous
//
#include <hip/hip_runtime.h>
#include <hip/hip_bf16.h>
#include <stdint.h>

typedef __hip_bfloat16 bf16;
typedef __bf16 bf16x8 __attribute__((ext_vector_type(8)));
typedef float f32x4 __attribute__((ext_vector_type(4)));
typedef unsigned short u16x8 __attribute__((ext_vector_type(8)));

#define HID   768
#define SEQL  40
#define TOK   185          // 40 text + 1 cls + 144 patches
#define NP    144
#define PD2   12
#define KDIM  3072
#define IMGSZ 384
#define IMG2  147456       // 384*384

// ws layout: [0, 56623104) pixel bf16 ; [56623104, 61341696) conv_w bf16 ; then int tables
#define WSB_PIX 0
#define WSB_W   56623104
#define WSB_INT 61341696
#define WS_DST 0
#define WS_SRC 9216
#define WS_MV  18432
#define WS_XH  27648
#define WS_XW  27712

#define EMB_ELEMS (64 * TOK * HID)

// fused pre-kernel block ranges
#define NB_PIXC 2048
#define NB_WC   128
#define NB_TEXT (64 * SEQL)
#define BID_WC   NB_PIXC
#define BID_TEXT (NB_PIXC + NB_WC)
#define BID_PREP (BID_TEXT + NB_TEXT)
#define BID_CLS  (BID_PREP + 64)
#define NB_TOTAL (BID_CLS + 64)

#define N8_PIX (28311552 / 8)
#define N8_W   (2359296 / 8)

__device__ __forceinline__ unsigned short f2bu(float x) {   // f32 -> bf16 bits, RNE
    uint32_t u = __float_as_uint(x);
    return (unsigned short)((u + 0x7FFFu + ((u >> 16) & 1u)) >> 16);
}

// ---------------------------------------------------------------- fused pre: casts + text LN + prep + cls/masks
__global__ __launch_bounds__(256) void pre_kernel(
    const float* __restrict__ pixf, unsigned short* __restrict__ pixb,
    const float* __restrict__ Wc, unsigned short* __restrict__ wb,
    const int* __restrict__ ids, const int* __restrict__ tts,
    const float* __restrict__ wemb, const float* __restrict__ ptext,
    const float* __restrict__ ttemb, const float* __restrict__ g,
    const float* __restrict__ be, const float* __restrict__ modal,
    const int* __restrict__ pmask, const float* __restrict__ cls,
    const float* __restrict__ vpos, const int* __restrict__ tti,
    const int* __restrict__ attn, int* __restrict__ ws,
    float* __restrict__ out) {
    int bid = blockIdx.x, tid = threadIdx.x;
    if (bid < NB_PIXC) {
        for (int i = bid * 256 + tid; i < N8_PIX; i += NB_PIXC * 256) {
            f32x4 a = ((const f32x4*)pixf)[2 * i];
            f32x4 b = ((const f32x4*)pixf)[2 * i + 1];
            u16x8 r;
#pragma unroll
            for (int j = 0; j < 4; j++) r[j] = f2bu(a[j]);
#pragma unroll
            for (int j = 0; j < 4; j++) r[4 + j] = f2bu(b[j]);
            ((u16x8*)pixb)[i] = r;
        }
    } else if (bid < BID_TEXT) {
        for (int i = (bid - BID_WC) * 256 + tid; i < N8_W; i += NB_WC * 256) {
            f32x4 a = ((const f32x4*)Wc)[2 * i];
            f32x4 b = ((const f32x4*)Wc)[2 * i + 1];
            u16x8 r;
#pragma unroll
            for (int j = 0; j < 4; j++) r[j] = f2bu(a[j]);
#pragma unroll
            for (int j = 0; j < 4; j++) r[4 + j] = f2bu(b[j]);
            ((u16x8*)wb)[i] = r;
        }
    } else if (bid < BID_PREP) {
        int blk = bid - BID_TEXT;
        int b = blk / SEQL, s = blk % SEQL;
        int id = ids[b * SEQL + s];
        int tt = tts[b * SEQL + s];
        const float* wr = wemb + (size_t)id * HID;
        const float* tr = ttemb + (size_t)tt * HID;
        const float* pr = ptext + s * HID;
        float x[3], s1 = 0.f, s2 = 0.f;
#pragma unroll
        for (int k = 0; k < 3; k++) {
            int n = tid + k * 256;
            float xv = wr[n] + tr[n] + pr[n];
            x[k] = xv; s1 += xv; s2 += xv * xv;
        }
        for (int off = 32; off; off >>= 1) {
            s1 += __shfl_down(s1, off);
            s2 += __shfl_down(s2, off);
        }
        __shared__ float red[8];
        int lane = tid & 63, wid = tid >> 6;
        if (lane == 0) { red[wid] = s1; red[4 + wid] = s2; }
        __syncthreads();
        float ts1 = red[0] + red[1] + red[2] + red[3];
        float ts2 = red[4] + red[5] + red[6] + red[7];
        float mu = ts1 * (1.0f / HID);
        float var = ts2 * (1.0f / HID) - mu * mu;
        float rstd = rsqrtf(var + 1e-12f);
        float* orow = out + ((size_t)(b * TOK + s)) * HID;
#pragma unroll
        for (int k = 0; k < 3; k++) {
            int n = tid + k * 256;
            orow[n] = (x[k] - mu) * rstd * g[n] + be[n] + modal[n];
        }
    } else if (bid < BID_CLS) {
        int b = bid - BID_PREP;
        __shared__ int v[NP];
        if (tid < NP) {
            int i = tid / PD2, j = tid % PD2;
            v[tid] = pmask[(size_t)b * IMG2 + (size_t)(i * 32) * IMGSZ + (j * 32)];
        }
        __syncthreads();
        if (tid == 0) {
            int nv = 0;
            for (int p = 0; p < NP; p++) nv += (v[p] != 0);
            int cv = 0, ci = 0;
            for (int p = 0; p < NP; p++) {
                int d = v[p] ? (cv++) : (nv + ci++);
                ws[WS_DST + b * NP + p] = d;
                ws[WS_SRC + b * NP + d] = p;
                ws[WS_MV + b * NP + p] = v[p];
            }
            int h = 0, w = 0;
            for (int i = 0; i < PD2; i++) h += v[i * PD2];
            for (int j = 0; j < PD2; j++) w += v[j];
            ws[WS_XH + b] = h;
            ws[WS_XW + b] = w;
        }
    } else {
        int b = bid - BID_CLS;
        int tt = *tti;
        const float* modalr = modal + tt * HID;
        float* orow = out + ((size_t)(b * TOK + SEQL)) * HID;
#pragma unroll
        for (int k = 0; k < 3; k++) {
            int n = tid + k * 256;
            orow[n] = cls[n] + vpos[n] + modalr[n];
        }
        __shared__ int v2[NP];
        if (tid < NP) {
            int i = tid / PD2, j = tid % PD2;
            v2[tid] = pmask[(size_t)b * IMG2 + (size_t)(i * 32) * IMGSZ + (j * 32)];
        }
        __syncthreads();
        __shared__ int srcl[NP];
        if (tid == 0) {
            int nv = 0;
            for (int p = 0; p < NP; p++) nv += (v2[p] != 0);
            int cv = 0, ci = 0;
            for (int p = 0; p < NP; p++) {
                int d = v2[p] ? (cv++) : (nv + ci++);
                srcl[d] = p;
            }
        }
        __syncthreads();
        float* om = out + (size_t)EMB_ELEMS + (size_t)b * TOK;
        if (tid < TOK) {
            float mv;
            if (tid < SEQL) mv = (float)attn[b * SEQL + tid];
            else if (tid == SEQL) mv = 1.0f;
            else mv = (float)v2[srcl[tid - (SEQL + 1)]];
            om[tid] = mv;
        }
    }
}

// ---------------------------------------------------------------- conv GEMM
// 128x128 tiles, 64x64 wave tiles, 2-phase dbuf: stage(next) -> compute(cur), 1 barrier/K-step.
// T5: setprio(1) around MFMA cluster (dbuf gives wave role-diversity).
__global__ __launch_bounds__(256, 2) void gemm_kernel(
    const bf16* __restrict__ pix, const bf16* __restrict__ W,
    const float* __restrict__ bias, const float* __restrict__ vpos,
    const float* __restrict__ modal, const int* __restrict__ tti,
    const int* __restrict__ ws, float* __restrict__ out) {
    __shared__ unsigned short As[2 * 128 * 64];   // 32 KB
    __shared__ unsigned short Bs[2 * 128 * 64];   // 32 KB

    int bid = blockIdx.x;
    int swz = (bid & 7) * 54 + (bid >> 3);   // 432 = 8*54, bijective XCD swizzle
    int bm = swz / 6, bn = swz - bm * 6;     // n fastest: 6 blocks share an A panel
    int m0 = bm << 7, n0 = bn << 7;

    int tid = threadIdx.x;
    int lane = tid & 63, wid = tid >> 6;
    int wm = wid >> 1, wn = wid & 1;         // 2x2 wave grid, wave tile 64x64

    // staging: thread covers LDS slot (row, kof); source k pre-swizzled (rule 21)
    int kof = (tid & 7) << 3;                // dest k offset within BK=64
    size_t apix[4]; size_t wbase[4]; int kofs[4];
#pragma unroll
    for (int r = 0; r < 4; r++) {
        int row = (tid >> 3) + r * 32;       // 0..127
        kofs[r] = kof ^ ((row & 7) << 3);    // swizzled source k offset
        int gm = m0 + row;
        int b_ = gm / NP; int p_ = gm - b_ * NP;
        int ii = p_ / PD2, jj = p_ - ii * PD2;
        apix[r] = (size_t)(b_ * 3) * IMG2 + (size_t)(ii * 32) * IMGSZ + (jj * 32);
        wbase[r] = (size_t)(n0 + row) * KDIM + kofs[r];
    }

    f32x4 acc[4][4];
#pragma unroll
    for (int a = 0; a < 4; a++)
#pragma unroll
        for (int c = 0; c < 4; c++) acc[a][c] = (f32x4){0.f, 0.f, 0.f, 0.f};

#define STAGE(BUF, KT)                                                              \
    {                                                                               \
        _Pragma("unroll")                                                           \
        for (int r = 0; r < 4; r++) {                                               \
            int k = (KT) + kofs[r];                                                 \
            int ci = k >> 10; int rem = k & 1023;                                   \
            size_t cioff = (size_t)ci * IMG2 + (size_t)(rem >> 5) * IMGSZ + (rem & 31); \
            const bf16* ga = pix + apix[r] + cioff;                                 \
            const bf16* gb = W + wbase[r] + (KT);                                   \
            unsigned short* la = As + (BUF) * 8192 + r * 2048 + wid * 512;          \
            unsigned short* lb = Bs + (BUF) * 8192 + r * 2048 + wid * 512;          \
            __builtin_amdgcn_global_load_lds(                                       \
                (const __attribute__((address_space(1))) unsigned int*)ga,          \
                (__attribute__((address_space(3))) unsigned int*)la, 16, 0, 0);     \
            __builtin_amdgcn_global_load_lds(                                       \
                (const __attribute__((address_space(1))) unsigned int*)gb,          \
                (__attribute__((address_space(3))) unsigned int*)lb, 16, 0, 0);     \
        }                                                                           \
    }

#define COMPUTE(BUF)                                                                \
    {                                                                               \
        _Pragma("unroll")                                                           \
        for (int ks = 0; ks < 2; ks++) {                                            \
            int kb = (ks << 5) + ((lane >> 4) << 3);                                \
            bf16x8 af[4], bfr[4];                                                   \
            _Pragma("unroll")                                                       \
            for (int mi = 0; mi < 4; mi++) {                                        \
                int row = (wm << 6) + (mi << 4) + (lane & 15);                      \
                af[mi] = *(const bf16x8*)&As[(BUF) * 8192 + row * 64 + (kb ^ ((row & 7) << 3))]; \
            }                                                                       \
            _Pragma("unroll")                                                       \
            for (int nj = 0; nj < 4; nj++) {                                        \
                int row = (wn << 6) + (nj << 4) + (lane & 15);                      \
                bfr[nj] = *(const bf16x8*)&Bs[(BUF) * 8192 + row * 64 + (kb ^ ((row & 7) << 3))]; \
            }                                                                       \
            __builtin_amdgcn_s_setprio(1);                                          \
            _Pragma("unroll")                                                       \
            for (int mi = 0; mi < 4; mi++)                                          \
                _Pragma("unroll")                                                   \
                for (int nj = 0; nj < 4; nj++)                                      \
                    acc[mi][nj] = __builtin_amdgcn_mfma_f32_16x16x32_bf16(          \
                        af[mi], bfr[nj], acc[mi][nj], 0, 0, 0);                     \
            __builtin_amdgcn_s_setprio(0);                                          \
        }                                                                           \
    }

    STAGE(0, 0);
    for (int kt = 0; kt < KDIM; kt += 64) {
        int buf = (kt >> 6) & 1;
        __syncthreads();                     // drains stage -> buf ready
        if (kt + 64 < KDIM) STAGE(buf ^ 1, kt + 64);   // issue next tile early
        COMPUTE(buf);
    }
#undef STAGE
#undef COMPUTE

    // -------- epilogue: +bias +bilinear pos +modality, scatter to token rows (f32 out)
    int tt = *tti;
    const float* modalr = modal + tt * HID;
    int r16 = lane >> 4, c16 = lane & 15;
#pragma unroll
    for (int mi = 0; mi < 4; mi++) {
#pragma unroll
        for (int reg = 0; reg < 4; reg++) {
            int gm = m0 + (wm << 6) + (mi << 4) + (r16 << 2) + reg;
            int b_ = gm / NP; int p_ = gm - b_ * NP;
            int ii = p_ / PD2, jj = p_ - ii * PD2;
            int h = ws[WS_XH + b_], w = ws[WS_XW + b_];
            float hf = (float)((h - 1) > 1 ? (h - 1) : 1);
            float wf = (float)((w - 1) > 1 ? (w - 1) : 1);
            float ry = (float)(ii * (PD2 - 1)) / hf;
            float rx = (float)(jj * (PD2 - 1)) / wf;
            int y0 = (int)floorf(ry); y0 = y0 < 0 ? 0 : (y0 > PD2 - 1 ? PD2 - 1 : y0);
            int x0 = (int)floorf(rx); x0 = x0 < 0 ? 0 : (x0 > PD2 - 1 ? PD2 - 1 : x0);
            int y1 = y0 + 1 > PD2 - 1 ? PD2 - 1 : y0 + 1;
            int x1 = x0 + 1 > PD2 - 1 ? PD2 - 1 : x0 + 1;
            float wy = ry - (float)y0, wx = rx - (float)x0;
            float vs = ((ii < h) && (jj < w)) ? 1.0f : 0.0f;
            float w00 = (1.f - wy) * (1.f - wx) * vs, w01 = (1.f - wy) * wx * vs;
            float w10 = wy * (1.f - wx) * vs, w11 = wy * wx * vs;
            const float* p00 = vpos + (size_t)(1 + y0 * PD2 + x0) * HID;
            const float* p01 = vpos + (size_t)(1 + y0 * PD2 + x1) * HID;
            const float* p10 = vpos + (size_t)(1 + y1 * PD2 + x0) * HID;
            const float* p11 = vpos + (size_t)(1 + y1 * PD2 + x1) * HID;
            int drow = ws[WS_DST + b_ * NP + p_];
            float* orow = out + ((size_t)(b_ * TOK + SEQL + 1 + drow)) * HID;
#pragma unroll
            for (int nj = 0; nj < 4; nj++) {
                int n = n0 + (wn << 6) + (nj << 4) + c16;
                float pos = w00 * p00[n] + w01 * p01[n] + w10 * p10[n] + w11 * p11[n];
                orow[n] = acc[mi][nj][reg] + bias[n] + pos + modalr[n];
            }
        }
    }
}

// ---------------------------------------------------------------- launch
extern "C" void kernel_launch(void* const* d_in, const int* in_sizes, int n_in,
                              void* d_out, int out_size, void* d_ws, size_t ws_size,
                              hipStream_t stream) {
    const int* ids = (const int*)d_in[0];
    const int* attn = (const int*)d_in[1];
    const int* tts = (const int*)d_in[2];
    const float* pix = (const float*)d_in[3];
    const int* pmask = (const int*)d_in[4];
    const float* wemb = (const float*)d_in[5];
    const float* ptext = (const float*)d_in[6];
    const float* ttemb = (const float*)d_in[7];
    const float* g = (const float*)d_in[8];
    const float* be = (const float*)d_in[9];
    const float* cls = (const float*)d_in[10];
    const float* Wc = (const float*)d_in[11];
    const float* bias = (const float*)d_in[12];
    const float* vpos = (const float*)d_in[13];
    const float* modal = (const float*)d_in[14];
    const int* tti = (const int*)d_in[15];
    float* out = (float*)d_out;

    unsigned short* pixb = (unsigned short*)((char*)d_ws + WSB_PIX);
    unsigned short* wb = (unsigned short*)((char*)d_ws + WSB_W);
    int* wsi = (int*)((char*)d_ws + WSB_INT);

    pre_kernel<<<NB_TOTAL, 256, 0, stream>>>(pix, pixb, Wc, wb, ids, tts, wemb, ptext,
                                             ttemb, g, be, modal, pmask, cls, vpos, tti,
                                             attn, wsi, out);
    gemm_kernel<<<432, 256, 0, stream>>>((const bf16*)pixb, (const bf16*)wb,
                                         bias, vpos, modal, tti, wsi, out);
}

// Round 15
// 100.563 us; speedup vs baseline: 1.3451x; 1.0410x over previous
//
#include <hip/hip_runtime.h>
#include <hip/hip_bf16.h>
#include <stdint.h>

typedef __hip_bfloat16 bf16;
typedef __bf16 bf16x8 __attribute__((ext_vector_type(8)));
typedef float f32x4 __attribute__((ext_vector_type(4)));
typedef unsigned short u16x8 __attribute__((ext_vector_type(8)));

#define HID   768
#define SEQL  40
#define TOK   185          // 40 text + 1 cls + 144 patches
#define NP    144
#define PD2   12
#define KDIM  3072
#define IMGSZ 384
#define IMG2  147456       // 384*384

// ws layout: [0, 56623104) pixel bf16 ; [56623104, 61341696) conv_w bf16 ; then int tables
#define WSB_PIX 0
#define WSB_W   56623104
#define WSB_INT 61341696
#define WS_DST 0
#define WS_SRC 9216
#define WS_MV  18432
#define WS_XH  27648
#define WS_XW  27712

#define EMB_ELEMS (64 * TOK * HID)

// pre kernel: casts + prep only
#define NB_PIXC 2048
#define NB_WC   128
#define BID_PREP (NB_PIXC + NB_WC)
#define NB_PRE   (BID_PREP + 64)

// merged main kernel: gemm first, then aux
#define NB_GEMM 432
#define NB_TEXT (64 * SEQL)
#define BID_TEXT NB_GEMM
#define BID_CLS  (BID_TEXT + NB_TEXT)
#define NB_MAIN  (BID_CLS + 64)

#define N8_PIX (28311552 / 8)
#define N8_W   (2359296 / 8)

__device__ __forceinline__ unsigned short f2bu(float x) {   // f32 -> bf16 bits, RNE
    uint32_t u = __float_as_uint(x);
    return (unsigned short)((u + 0x7FFFu + ((u >> 16) & 1u)) >> 16);
}

// ---------------------------------------------------------------- pre: casts + prep
__global__ __launch_bounds__(256) void pre_kernel(
    const float* __restrict__ pixf, unsigned short* __restrict__ pixb,
    const float* __restrict__ Wc, unsigned short* __restrict__ wb,
    const int* __restrict__ pmask, int* __restrict__ ws) {
    int bid = blockIdx.x, tid = threadIdx.x;
    if (bid < NB_PIXC) {
        for (int i = bid * 256 + tid; i < N8_PIX; i += NB_PIXC * 256) {
            f32x4 a = ((const f32x4*)pixf)[2 * i];
            f32x4 b = ((const f32x4*)pixf)[2 * i + 1];
            u16x8 r;
#pragma unroll
            for (int j = 0; j < 4; j++) r[j] = f2bu(a[j]);
#pragma unroll
            for (int j = 0; j < 4; j++) r[4 + j] = f2bu(b[j]);
            ((u16x8*)pixb)[i] = r;
        }
    } else if (bid < BID_PREP) {
        for (int i = (bid - NB_PIXC) * 256 + tid; i < N8_W; i += NB_WC * 256) {
            f32x4 a = ((const f32x4*)Wc)[2 * i];
            f32x4 b = ((const f32x4*)Wc)[2 * i + 1];
            u16x8 r;
#pragma unroll
            for (int j = 0; j < 4; j++) r[j] = f2bu(a[j]);
#pragma unroll
            for (int j = 0; j < 4; j++) r[4 + j] = f2bu(b[j]);
            ((u16x8*)wb)[i] = r;
        }
    } else {
        int b = bid - BID_PREP;
        __shared__ int v[NP];
        if (tid < NP) {
            int i = tid / PD2, j = tid % PD2;
            v[tid] = pmask[(size_t)b * IMG2 + (size_t)(i * 32) * IMGSZ + (j * 32)];
        }
        __syncthreads();
        if (tid == 0) {
            int nv = 0;
            for (int p = 0; p < NP; p++) nv += (v[p] != 0);
            int cv = 0, ci = 0;
            for (int p = 0; p < NP; p++) {
                int d = v[p] ? (cv++) : (nv + ci++);
                ws[WS_DST + b * NP + p] = d;
                ws[WS_SRC + b * NP + d] = p;
                ws[WS_MV + b * NP + p] = v[p];
            }
            int h = 0, w = 0;
            for (int i = 0; i < PD2; i++) h += v[i * PD2];
            for (int j = 0; j < PD2; j++) w += v[j];
            ws[WS_XH + b] = h;
            ws[WS_XW + b] = w;
        }
    }
}

// ---------------------------------------------------------------- merged main: GEMM (bid<432) + text LN + cls/masks
// GEMM: 128x128 tiles, 64x64 wave tiles, 2-phase dbuf, 1 barrier/K-step, setprio on MFMA.
__global__ __launch_bounds__(256, 2) void main_kernel(
    const bf16* __restrict__ pix, const bf16* __restrict__ W,
    const float* __restrict__ bias, const float* __restrict__ vpos,
    const float* __restrict__ modal, const int* __restrict__ tti,
    const int* __restrict__ ws,
    const int* __restrict__ ids, const int* __restrict__ tts,
    const float* __restrict__ wemb, const float* __restrict__ ptext,
    const float* __restrict__ ttemb, const float* __restrict__ g,
    const float* __restrict__ be, const int* __restrict__ attn,
    const float* __restrict__ cls, float* __restrict__ out) {
    __shared__ unsigned short As[2 * 128 * 64];   // 32 KB
    __shared__ unsigned short Bs[2 * 128 * 64];   // 32 KB

    int bid0 = blockIdx.x;
    int tid = threadIdx.x;

    if (bid0 >= NB_GEMM) {
        if (bid0 < BID_CLS) {
            // ---- text embedding + LayerNorm ----
            int blk = bid0 - BID_TEXT;
            int b = blk / SEQL, s = blk % SEQL;
            int id = ids[b * SEQL + s];
            int tt = tts[b * SEQL + s];
            const float* wr = wemb + (size_t)id * HID;
            const float* tr = ttemb + (size_t)tt * HID;
            const float* pr = ptext + s * HID;
            float x[3], s1 = 0.f, s2 = 0.f;
#pragma unroll
            for (int k = 0; k < 3; k++) {
                int n = tid + k * 256;
                float xv = wr[n] + tr[n] + pr[n];
                x[k] = xv; s1 += xv; s2 += xv * xv;
            }
            for (int off = 32; off; off >>= 1) {
                s1 += __shfl_down(s1, off);
                s2 += __shfl_down(s2, off);
            }
            __shared__ float red[8];
            int lane = tid & 63, wid = tid >> 6;
            if (lane == 0) { red[wid] = s1; red[4 + wid] = s2; }
            __syncthreads();
            float ts1 = red[0] + red[1] + red[2] + red[3];
            float ts2 = red[4] + red[5] + red[6] + red[7];
            float mu = ts1 * (1.0f / HID);
            float var = ts2 * (1.0f / HID) - mu * mu;
            float rstd = rsqrtf(var + 1e-12f);
            float* orow = out + ((size_t)(b * TOK + s)) * HID;
            const float* modal0 = modal;   // text modality = row 0
#pragma unroll
            for (int k = 0; k < 3; k++) {
                int n = tid + k * 256;
                orow[n] = (x[k] - mu) * rstd * g[n] + be[n] + modal0[n];
            }
        } else {
            // ---- cls row + attention/image masks (prep tables already in ws) ----
            int b = bid0 - BID_CLS;
            int tt = *tti;
            const float* modalr = modal + tt * HID;
            float* orow = out + ((size_t)(b * TOK + SEQL)) * HID;
#pragma unroll
            for (int k = 0; k < 3; k++) {
                int n = tid + k * 256;
                orow[n] = cls[n] + vpos[n] + modalr[n];
            }
            float* om = out + (size_t)EMB_ELEMS + (size_t)b * TOK;
            if (tid < TOK) {
                float mv;
                if (tid < SEQL) mv = (float)attn[b * SEQL + tid];
                else if (tid == SEQL) mv = 1.0f;
                else {
                    int t = tid - (SEQL + 1);
                    int p = ws[WS_SRC + b * NP + t];
                    mv = (float)ws[WS_MV + b * NP + p];
                }
                om[tid] = mv;
            }
        }
        return;
    }

    // ---------------- GEMM path ----------------
    int bid = bid0;
    int swz = (bid & 7) * 54 + (bid >> 3);   // 432 = 8*54, bijective XCD swizzle
    int bm = swz / 6, bn = swz - bm * 6;     // n fastest: 6 blocks share an A panel
    int m0 = bm << 7, n0 = bn << 7;

    int lane = tid & 63, wid = tid >> 6;
    int wm = wid >> 1, wn = wid & 1;         // 2x2 wave grid, wave tile 64x64

    int kof = (tid & 7) << 3;                // dest k offset within BK=64
    size_t apix[4]; size_t wbase[4]; int kofs[4];
#pragma unroll
    for (int r = 0; r < 4; r++) {
        int row = (tid >> 3) + r * 32;       // 0..127
        kofs[r] = kof ^ ((row & 7) << 3);    // swizzled source k offset
        int gm = m0 + row;
        int b_ = gm / NP; int p_ = gm - b_ * NP;
        int ii = p_ / PD2, jj = p_ - ii * PD2;
        apix[r] = (size_t)(b_ * 3) * IMG2 + (size_t)(ii * 32) * IMGSZ + (jj * 32);
        wbase[r] = (size_t)(n0 + row) * KDIM + kofs[r];
    }

    f32x4 acc[4][4];
#pragma unroll
    for (int a = 0; a < 4; a++)
#pragma unroll
        for (int c = 0; c < 4; c++) acc[a][c] = (f32x4){0.f, 0.f, 0.f, 0.f};

#define STAGE(BUF, KT)                                                              \
    {                                                                               \
        _Pragma("unroll")                                                           \
        for (int r = 0; r < 4; r++) {                                               \
            int k = (KT) + kofs[r];                                                 \
            int ci = k >> 10; int rem = k & 1023;                                   \
            size_t cioff = (size_t)ci * IMG2 + (size_t)(rem >> 5) * IMGSZ + (rem & 31); \
            const bf16* ga = pix + apix[r] + cioff;                                 \
            const bf16* gb = W + wbase[r] + (KT);                                   \
            unsigned short* la = As + (BUF) * 8192 + r * 2048 + wid * 512;          \
            unsigned short* lb = Bs + (BUF) * 8192 + r * 2048 + wid * 512;          \
            __builtin_amdgcn_global_load_lds(                                       \
                (const __attribute__((address_space(1))) unsigned int*)ga,          \
                (__attribute__((address_space(3))) unsigned int*)la, 16, 0, 0);     \
            __builtin_amdgcn_global_load_lds(                                       \
                (const __attribute__((address_space(1))) unsigned int*)gb,          \
                (__attribute__((address_space(3))) unsigned int*)lb, 16, 0, 0);     \
        }                                                                           \
    }

#define COMPUTE(BUF)                                                                \
    {                                                                               \
        _Pragma("unroll")                                                           \
        for (int ks = 0; ks < 2; ks++) {                                            \
            int kb = (ks << 5) + ((lane >> 4) << 3);                                \
            bf16x8 af[4], bfr[4];                                                   \
            _Pragma("unroll")                                                       \
            for (int mi = 0; mi < 4; mi++) {                                        \
                int row = (wm << 6) + (mi << 4) + (lane & 15);                      \
                af[mi] = *(const bf16x8*)&As[(BUF) * 8192 + row * 64 + (kb ^ ((row & 7) << 3))]; \
            }                                                                       \
            _Pragma("unroll")                                                       \
            for (int nj = 0; nj < 4; nj++) {                                        \
                int row = (wn << 6) + (nj << 4) + (lane & 15);                      \
                bfr[nj] = *(const bf16x8*)&Bs[(BUF) * 8192 + row * 64 + (kb ^ ((row & 7) << 3))]; \
            }                                                                       \
            __builtin_amdgcn_s_setprio(1);                                          \
            _Pragma("unroll")                                                       \
            for (int mi = 0; mi < 4; mi++)                                          \
                _Pragma("unroll")                                                   \
                for (int nj = 0; nj < 4; nj++)                                      \
                    acc[mi][nj] = __builtin_amdgcn_mfma_f32_16x16x32_bf16(          \
                        af[mi], bfr[nj], acc[mi][nj], 0, 0, 0);                     \
            __builtin_amdgcn_s_setprio(0);                                          \
        }                                                                           \
    }

    STAGE(0, 0);
    for (int kt = 0; kt < KDIM; kt += 64) {
        int buf = (kt >> 6) & 1;
        __syncthreads();                     // drains stage -> buf ready
        if (kt + 64 < KDIM) STAGE(buf ^ 1, kt + 64);   // issue next tile early
        COMPUTE(buf);
    }
#undef STAGE
#undef COMPUTE

    // -------- epilogue: +bias +bilinear pos +modality, scatter to token rows (f32 out)
    int tt = *tti;
    const float* modalr = modal + tt * HID;
    int r16 = lane >> 4, c16 = lane & 15;
#pragma unroll
    for (int mi = 0; mi < 4; mi++) {
#pragma unroll
        for (int reg = 0; reg < 4; reg++) {
            int gm = m0 + (wm << 6) + (mi << 4) + (r16 << 2) + reg;
            int b_ = gm / NP; int p_ = gm - b_ * NP;
            int ii = p_ / PD2, jj = p_ - ii * PD2;
            int h = ws[WS_XH + b_], w = ws[WS_XW + b_];
            float hf = (float)((h - 1) > 1 ? (h - 1) : 1);
            float wf = (float)((w - 1) > 1 ? (w - 1) : 1);
            float ry = (float)(ii * (PD2 - 1)) / hf;
            float rx = (float)(jj * (PD2 - 1)) / wf;
            int y0 = (int)floorf(ry); y0 = y0 < 0 ? 0 : (y0 > PD2 - 1 ? PD2 - 1 : y0);
            int x0 = (int)floorf(rx); x0 = x0 < 0 ? 0 : (x0 > PD2 - 1 ? PD2 - 1 : x0);
            int y1 = y0 + 1 > PD2 - 1 ? PD2 - 1 : y0 + 1;
            int x1 = x0 + 1 > PD2 - 1 ? PD2 - 1 : x0 + 1;
            float wy = ry - (float)y0, wx = rx - (float)x0;
            float vs = ((ii < h) && (jj < w)) ? 1.0f : 0.0f;
            float w00 = (1.f - wy) * (1.f - wx) * vs, w01 = (1.f - wy) * wx * vs;
            float w10 = wy * (1.f - wx) * vs, w11 = wy * wx * vs;
            const float* p00 = vpos + (size_t)(1 + y0 * PD2 + x0) * HID;
            const float* p01 = vpos + (size_t)(1 + y0 * PD2 + x1) * HID;
            const float* p10 = vpos + (size_t)(1 + y1 * PD2 + x0) * HID;
            const float* p11 = vpos + (size_t)(1 + y1 * PD2 + x1) * HID;
            int drow = ws[WS_DST + b_ * NP + p_];
            float* orow = out + ((size_t)(b_ * TOK + SEQL + 1 + drow)) * HID;
#pragma unroll
            for (int nj = 0; nj < 4; nj++) {
                int n = n0 + (wn << 6) + (nj << 4) + c16;
                float pos = w00 * p00[n] + w01 * p01[n] + w10 * p10[n] + w11 * p11[n];
                orow[n] = acc[mi][nj][reg] + bias[n] + pos + modalr[n];
            }
        }
    }
}

// ---------------------------------------------------------------- launch
extern "C" void kernel_launch(void* const* d_in, const int* in_sizes, int n_in,
                              void* d_out, int out_size, void* d_ws, size_t ws_size,
                              hipStream_t stream) {
    const int* ids = (const int*)d_in[0];
    const int* attn = (const int*)d_in[1];
    const int* tts = (const int*)d_in[2];
    const float* pix = (const float*)d_in[3];
    const int* pmask = (const int*)d_in[4];
    const float* wemb = (const float*)d_in[5];
    const float* ptext = (const float*)d_in[6];
    const float* ttemb = (const float*)d_in[7];
    const float* g = (const float*)d_in[8];
    const float* be = (const float*)d_in[9];
    const float* cls = (const float*)d_in[10];
    const float* Wc = (const float*)d_in[11];
    const float* bias = (const float*)d_in[12];
    const float* vpos = (const float*)d_in[13];
    const float* modal = (const float*)d_in[14];
    const int* tti = (const int*)d_in[15];
    float* out = (float*)d_out;

    unsigned short* pixb = (unsigned short*)((char*)d_ws + WSB_PIX);
    unsigned short* wb = (unsigned short*)((char*)d_ws + WSB_W);
    int* wsi = (int*)((char*)d_ws + WSB_INT);

    pre_kernel<<<NB_PRE, 256, 0, stream>>>(pix, pixb, Wc, wb, pmask, wsi);
    main_kernel<<<NB_MAIN, 256, 0, stream>>>((const bf16*)pixb, (const bf16*)wb,
                                             bias, vpos, modal, tti, wsi,
                                             ids, tts, wemb, ptext, ttemb, g, be,
                                             attn, cls, out);
}